// Round 7
// baseline (192.184 us; speedup 1.0000x reference)
//
#include <hip/hip_runtime.h>

// AutoregressiveLSTM: B=16384, T=100, HID=10, IN=OUT=4, P=5, Tp=96.
// 10 lanes/batch (lane u owns unit u's 4 gate rows), 6 groups/wave, 4 waves ->
// 24 batches per 256-thread block.
// Round 7: one-step-deferred rollout pipeline, FIXED consume placement.
// Body t = { h2m <- h2n (h_{t-1});  MAIN(t);  ROLLOUT(t-1) }.
// (Round 6 consumed at body END, so body t=1 ran MAIN/ROLLOUT with h=0 ->
// one-step state corruption, absmax 0.07.)  MAIN(t)'s h-readback (ds_read of
// row t&1) is consumed at the top of body t+1; the ~900 issue-cycles of
// ROLLOUT(t-1) sit inside that window, hiding all LDS latency on the chain.
// Main cell direct form (W_hh); rollout cells folded W_comb = W_hh + W_ih@W_lin.
// h rows: {0,1} = main-h double buffer (t&1), {2..5} = rollout h1..h4.

#define HIDN 10
#define INPN 4
#define OUTN 4
#define PN   5
#define TN   100
#define TPN  96
#define BN   16384
#define GPB  24   // batches per 256-thread block

typedef float v2f __attribute__((ext_vector_type(2)));

#define PIN(x) asm volatile("" : "+v"(x))

__device__ __forceinline__ float rcpf_(float v) { return __builtin_amdgcn_rcpf(v); }
__device__ __forceinline__ float e2_(float v)   { return __builtin_amdgcn_exp2f(v); }
// pre-scaled by log2(e):  sigmoid(x) = 1/(1+2^(-g))
__device__ __forceinline__ float sig2_(float g)  { return rcpf_(1.0f + e2_(-g)); }
// pre-scaled by 2*log2(e): tanh(x) = 1 - 2/(1+2^g)
__device__ __forceinline__ float tanh2_(float g) { return fmaf(-2.0f, rcpf_(1.0f + e2_(g)), 1.0f); }

#define K2L2E 2.88539008177792681472f  // 2*log2(e), for tanh(c)

__global__ __launch_bounds__(256, 2) void lstm_ar_kernel(
    const float* __restrict__ x,      // [B, T, IN]
    const float* __restrict__ W_ih,   // [40, 4]
    const float* __restrict__ W_hh,   // [40, 10]
    const float* __restrict__ b_ih,   // [40]
    const float* __restrict__ b_hh,   // [40]
    const float* __restrict__ W_lin,  // [4, 10]
    const float* __restrict__ b_lin,  // [4]
    float* __restrict__ out)          // [B*Tp*P*OUT] ++ [B*HID]
{
    // rows 0,1: main-h double buffer; rows 2..5: rollout h1..h4. 80B row stride.
    __shared__ __align__(16) float s_h[GPB][6][20];

    const int tid = threadIdx.x;
    const int wid = tid >> 6;
    const int wl  = tid & 63;
    const int grp = wl / 10;
    const int u   = wl - grp * 10;
    const int slot  = wid * 6 + grp;
    const int batch = blockIdx.x * GPB + slot;
    if (grp >= 6 || batch >= BN) return;

    // ---- per-lane weights (rows u, u+10, u+20, u+30 = i,f,g,o) ----
    const float L2E = 1.44269504088896340736f;
    const float rs[4] = { L2E, L2E, 2.0f * L2E, L2E };

    v2f  wm2[4][5];   // scaled W_hh rows   (main cell, direct form)
    v2f  wc2[4][5];   // scaled W_comb rows (rollout)
    v2f  wih2[4][2];  // scaled W_ih rows   (main cell)
    v2f  bm2[4];      // {scaled (b_ih+b_hh), 0}
    v2f  br2[4];      // {scaled folded rollout bias, 0}
    #pragma unroll
    for (int r = 0; r < 4; ++r) {
        const int j = u + r * 10;
        float wihr[INPN];
        #pragma unroll
        for (int q = 0; q < INPN; ++q) wihr[q] = W_ih[j * INPN + q];
        float bmr = b_ih[j] + b_hh[j];
        float brr = bmr;
        #pragma unroll
        for (int q = 0; q < INPN; ++q) brr += wihr[q] * b_lin[q];
        #pragma unroll
        for (int k = 0; k < HIDN; ++k) {
            float wmk = W_hh[j * HIDN + k];
            float wck = wmk;
            #pragma unroll
            for (int q = 0; q < INPN; ++q) wck += wihr[q] * W_lin[q * HIDN + k];
            if (k & 1) { wm2[r][k >> 1].y = wmk * rs[r]; wc2[r][k >> 1].y = wck * rs[r]; }
            else       { wm2[r][k >> 1].x = wmk * rs[r]; wc2[r][k >> 1].x = wck * rs[r]; }
        }
        #pragma unroll
        for (int q = 0; q < INPN; ++q) {
            if (q & 1) wih2[r][q >> 1].y = wihr[q] * rs[r];
            else       wih2[r][q >> 1].x = wihr[q] * rs[r];
        }
        bm2[r] = v2f{ bmr * rs[r], 0.0f };
        br2[r] = v2f{ brr * rs[r], 0.0f };
    }

    // ---- y weights: lane u -> y[pmine][opair..opair+1] ----
    const int pmine = u >> 1;
    const int opair = (u & 1) * 2;
    v2f yl0[5], yl1[5];
    #pragma unroll
    for (int k = 0; k < HIDN; k += 2) {
        yl0[k >> 1] = v2f{ W_lin[opair * HIDN + k],       W_lin[opair * HIDN + k + 1] };
        yl1[k >> 1] = v2f{ W_lin[(opair + 1) * HIDN + k], W_lin[(opair + 1) * HIDN + k + 1] };
    }
    v2f ybv0 = v2f{ b_lin[opair],     0.0f };
    v2f ybv1 = v2f{ b_lin[opair + 1], 0.0f };

    // ---- pin weights ----
    #pragma unroll
    for (int r = 0; r < 4; ++r) {
        #pragma unroll
        for (int k = 0; k < 5; ++k) { PIN(wm2[r][k]); PIN(wc2[r][k]); }
        PIN(wih2[r][0]); PIN(wih2[r][1]); PIN(bm2[r]); PIN(br2[r]);
    }
    #pragma unroll
    for (int k = 0; k < 5; ++k) { PIN(yl0[k]); PIN(yl1[k]); }
    PIN(ybv0); PIN(ybv1);

    const float* xb   = x + (long)batch * TN * INPN;
    float*       outb = out + (long)batch * TPN * PN * OUTN;

    float cm = 0.0f;       // c along the main chain
    v2f h2m[5], h2n[5];    // h_{t-1} (stable this body) / pending h_t readback
    #pragma unroll
    for (int k = 0; k < 5; ++k) h2m[k] = v2f{0.0f, 0.0f};

    // activation block: gates -> (c update, h_new)
    auto CELL = [&](const float g[4], float& c) -> float {
        float iv = sig2_(g[0]), fv = sig2_(g[1]), gv = tanh2_(g[2]), ov = sig2_(g[3]);
        c = fmaf(fv, c, iv * gv);
        return ov * tanh2_(c * K2L2E);
    };

    // MAIN(t): gates = wm@h2m + wih@x + bm; writes h_t to row t&1; issues
    // readback into h2n (consumed at the TOP of body t+1).
    auto MAIN = [&](int t, float4 xv) {
        v2f xa = v2f{xv.x, xv.y}, xc = v2f{xv.z, xv.w};
        float g[4];
        #pragma unroll
        for (int r = 0; r < 4; ++r) {
            v2f acc = bm2[r];
            acc = __builtin_elementwise_fma(wih2[r][0], xa, acc);
            acc = __builtin_elementwise_fma(wih2[r][1], xc, acc);
            #pragma unroll
            for (int k = 0; k < 5; ++k)
                acc = __builtin_elementwise_fma(wm2[r][k], h2m[k], acc);
            g[r] = acc.x + acc.y;
        }
        float hn = CELL(g, cm);
        s_h[slot][t & 1][u] = hn;
        __builtin_amdgcn_wave_barrier();
        const v2f* hp = (const v2f*)&s_h[slot][t & 1][0];
        #pragma unroll
        for (int k = 0; k < 5; ++k) h2n[k] = hp[k];
    };

    // ROLLOUT(tt): cells p=1..4 starting from h_tt (= h2m regs), c = cro;
    // then the y phase for step tt (5 outputs), store to outb + tt*20.
    auto ROLLOUT = [&](int tt, float cro) {
        v2f hr2[5];
        #pragma unroll
        for (int k = 0; k < 5; ++k) hr2[k] = h2m[k];
        float cr = cro;
        float g[4];
        #pragma unroll
        for (int p = 1; p < PN; ++p) {
            #pragma unroll
            for (int r = 0; r < 4; ++r) {
                v2f acc = br2[r];
                #pragma unroll
                for (int k = 0; k < 5; ++k)
                    acc = __builtin_elementwise_fma(wc2[r][k], hr2[k], acc);
                g[r] = acc.x + acc.y;
            }
            float hn = CELL(g, cr);
            s_h[slot][1 + p][u] = hn;
            __builtin_amdgcn_wave_barrier();
            if (p < PN - 1) {
                const v2f* hp = (const v2f*)&s_h[slot][1 + p][0];
                #pragma unroll
                for (int k = 0; k < 5; ++k) hr2[k] = hp[k];
            }
        }
        // y phase: lane u outputs y[tt][pmine][opair..opair+1].
        // pmine==0 -> main h_tt at row tt&1 (MAIN(tt+1) wrote the OTHER row);
        // pmine>=1 -> rollout h_p at row pmine+1.
        const int rowy = (pmine == 0) ? (tt & 1) : (pmine + 1);
        const v2f* hq = (const v2f*)&s_h[slot][rowy][0];
        v2f h0 = hq[0], h1 = hq[1], h3 = hq[2], h4 = hq[3], h5 = hq[4];
        v2f a0 = ybv0, a1 = ybv1;
        a0 = __builtin_elementwise_fma(yl0[0], h0, a0);
        a1 = __builtin_elementwise_fma(yl1[0], h0, a1);
        a0 = __builtin_elementwise_fma(yl0[1], h1, a0);
        a1 = __builtin_elementwise_fma(yl1[1], h1, a1);
        a0 = __builtin_elementwise_fma(yl0[2], h3, a0);
        a1 = __builtin_elementwise_fma(yl1[2], h3, a1);
        a0 = __builtin_elementwise_fma(yl0[3], h4, a0);
        a1 = __builtin_elementwise_fma(yl1[3], h4, a1);
        a0 = __builtin_elementwise_fma(yl0[4], h5, a0);
        a1 = __builtin_elementwise_fma(yl1[4], h5, a1);
        float2 yv; yv.x = a0.x + a0.y; yv.y = a1.x + a1.y;
        *(float2*)(outb + tt * PN * OUTN + 2 * u) = yv;
    };

    // ---- prologue: MAIN(0) ----
    float4 xcur = *(const float4*)xb;
    MAIN(0, xcur);                       // h2n = h_0 (pending)
    xcur = *(const float4*)(xb + INPN);

    // ---- pipelined loop: body t = { consume h_{t-1}; MAIN(t); ROLLOUT(t-1) } ----
    for (int t = 1; t < TPN; ++t) {
        float4 xnext = *(const float4*)(xb + (t + 1) * INPN);  // t+1 <= 96 < 100
        #pragma unroll
        for (int k = 0; k < 5; ++k) h2m[k] = h2n[k];  // h_{t-1} now available
        float cro = cm;          // c_{t-1}, for the deferred rollout
        MAIN(t, xcur);           // uses h_{t-1}; issues h_t readback into h2n
        ROLLOUT(t - 1, cro);     // uses h2m = h_{t-1}; fills the latency window
        xcur = xnext;
    }

    // ---- epilogue: rollout of the last step ----
    #pragma unroll
    for (int k = 0; k < 5; ++k) h2m[k] = h2n[k];      // h_95
    ROLLOUT(TPN - 1, cm);

    // ---- final cell state c (after main_95): [1, B, HID] ----
    out[(long)BN * TPN * PN * OUTN + (long)batch * HIDN + u] = cm;
}

extern "C" void kernel_launch(void* const* d_in, const int* in_sizes, int n_in,
                              void* d_out, int out_size, void* d_ws, size_t ws_size,
                              hipStream_t stream) {
    const float* x     = (const float*)d_in[0];
    const float* W_ih  = (const float*)d_in[1];
    const float* W_hh  = (const float*)d_in[2];
    const float* b_ih  = (const float*)d_in[3];
    const float* b_hh  = (const float*)d_in[4];
    const float* W_lin = (const float*)d_in[5];
    const float* b_lin = (const float*)d_in[6];
    float* out = (float*)d_out;

    const int grid = (BN + GPB - 1) / GPB;  // 683 blocks of 256 threads
    lstm_ar_kernel<<<grid, 256, 0, stream>>>(x, W_ih, W_hh, b_ih, b_hh, W_lin, b_lin, out);
}

// Round 8
// 191.612 us; speedup vs baseline: 1.0030x; 1.0030x over previous
//
#include <hip/hip_runtime.h>

// AutoregressiveLSTM: B=16384, T=100, HID=10, IN=OUT=4, P=5, Tp=96.
// 10 lanes/batch (lane u owns unit u's 4 gate rows), 6 groups/wave, 4 waves ->
// 24 batches per 256-thread block.
// Round 8: R5's small footprint (no wm set; MAIN uses folded W_comb with the
// rank-4 correction wih@(x - y_prev)) COMBINED with R7's deferred-rollout
// pipeline. y_prev = y[t-1][p=0] is computed at body top by lanes 0-1 from the
// just-consumed h2m registers (SY block), so MAIN(t) never waits on ROLLOUT.
// Body t = { h2m<-h2n; SY; MAIN(t); ROLLOUT(t-1) }. MAIN's h-readback is
// consumed at the NEXT body top, hidden under ~900 issue-cycles of ROLLOUT.
// 3 blocks/CU via __launch_bounds__(256,3) (R5-proven footprint).

#define HIDN 10
#define INPN 4
#define OUTN 4
#define PN   5
#define TN   100
#define TPN  96
#define BN   16384
#define GPB  24   // batches per 256-thread block

typedef float v2f __attribute__((ext_vector_type(2)));

#define PIN(x) asm volatile("" : "+v"(x))

__device__ __forceinline__ float rcpf_(float v) { return __builtin_amdgcn_rcpf(v); }
__device__ __forceinline__ float e2_(float v)   { return __builtin_amdgcn_exp2f(v); }
// pre-scaled by log2(e):  sigmoid(x) = 1/(1+2^(-g))
__device__ __forceinline__ float sig2_(float g)  { return rcpf_(1.0f + e2_(-g)); }
// pre-scaled by 2*log2(e): tanh(x) = 1 - 2/(1+2^g)
__device__ __forceinline__ float tanh2_(float g) { return fmaf(-2.0f, rcpf_(1.0f + e2_(g)), 1.0f); }

#define K2L2E 2.88539008177792681472f  // 2*log2(e), for tanh(c)

__global__ __launch_bounds__(256, 3) void lstm_ar_kernel(
    const float* __restrict__ x,      // [B, T, IN]
    const float* __restrict__ W_ih,   // [40, 4]
    const float* __restrict__ W_hh,   // [40, 10]
    const float* __restrict__ b_ih,   // [40]
    const float* __restrict__ b_hh,   // [40]
    const float* __restrict__ W_lin,  // [4, 10]
    const float* __restrict__ b_lin,  // [4]
    float* __restrict__ out)          // [B*Tp*P*OUT] ++ [B*HID]
{
    // rows 0,1: main-h double buffer (t&1); rows 2..5: rollout h1..h4.
    __shared__ __align__(16) float s_h[GPB][6][20];
    __shared__ __align__(16) float s_y[GPB][4];   // y[t-1][p=0], for MAIN's correction

    const int tid = threadIdx.x;
    const int wid = tid >> 6;
    const int wl  = tid & 63;
    const int grp = wl / 10;
    const int u   = wl - grp * 10;
    const int slot  = wid * 6 + grp;
    const int batch = blockIdx.x * GPB + slot;
    if (grp >= 6 || batch >= BN) return;

    // ---- per-lane folded weights (rows u, u+10, u+20, u+30 = i,f,g,o) ----
    const float L2E = 1.44269504088896340736f;
    const float rs[4] = { L2E, L2E, 2.0f * L2E, L2E };

    v2f  wc2[4][5];   // scaled W_comb rows = W_hh + W_ih@W_lin  (ALL cells)
    v2f  wih2[4][2];  // scaled W_ih rows (main-cell rank-4 correction)
    v2f  br2[4];      // {scaled folded bias (incl. wih@b_lin), 0}
    #pragma unroll
    for (int r = 0; r < 4; ++r) {
        const int j = u + r * 10;
        float wihr[INPN];
        #pragma unroll
        for (int q = 0; q < INPN; ++q) wihr[q] = W_ih[j * INPN + q];
        float brr = b_ih[j] + b_hh[j];
        #pragma unroll
        for (int q = 0; q < INPN; ++q) brr += wihr[q] * b_lin[q];
        #pragma unroll
        for (int k = 0; k < HIDN; ++k) {
            float wck = W_hh[j * HIDN + k];
            #pragma unroll
            for (int q = 0; q < INPN; ++q) wck += wihr[q] * W_lin[q * HIDN + k];
            if (k & 1) wc2[r][k >> 1].y = wck * rs[r];
            else       wc2[r][k >> 1].x = wck * rs[r];
        }
        #pragma unroll
        for (int q = 0; q < INPN; ++q) {
            if (q & 1) wih2[r][q >> 1].y = wihr[q] * rs[r];
            else       wih2[r][q >> 1].x = wihr[q] * rs[r];
        }
        br2[r] = v2f{ brr * rs[r], 0.0f };
    }

    // ---- y weights: lane u -> y[pmine][opair..opair+1] ----
    const int pmine = u >> 1;
    const int opair = (u & 1) * 2;
    v2f yl0[5], yl1[5];
    #pragma unroll
    for (int k = 0; k < HIDN; k += 2) {
        yl0[k >> 1] = v2f{ W_lin[opair * HIDN + k],       W_lin[opair * HIDN + k + 1] };
        yl1[k >> 1] = v2f{ W_lin[(opair + 1) * HIDN + k], W_lin[(opair + 1) * HIDN + k + 1] };
    }
    v2f ybv0 = v2f{ b_lin[opair],     0.0f };
    v2f ybv1 = v2f{ b_lin[opair + 1], 0.0f };

    // ---- pin weights (defeat re-load/remat inside the loop) ----
    #pragma unroll
    for (int r = 0; r < 4; ++r) {
        #pragma unroll
        for (int k = 0; k < 5; ++k) PIN(wc2[r][k]);
        PIN(wih2[r][0]); PIN(wih2[r][1]); PIN(br2[r]);
    }
    #pragma unroll
    for (int k = 0; k < 5; ++k) { PIN(yl0[k]); PIN(yl1[k]); }
    PIN(ybv0); PIN(ybv1);

    const float* xb   = x + (long)batch * TN * INPN;
    float*       outb = out + (long)batch * TPN * PN * OUTN;

    float cm = 0.0f;       // c along the main chain
    v2f h2m[5], h2n[5];    // h_{t-1} (stable this body) / pending h_t readback
    #pragma unroll
    for (int k = 0; k < 5; ++k) h2m[k] = v2f{0.0f, 0.0f};

    // activation block: gates -> (c update, h_new)
    auto CELL = [&](const float g[4], float& c) -> float {
        float iv = sig2_(g[0]), fv = sig2_(g[1]), gv = tanh2_(g[2]), ov = sig2_(g[3]);
        c = fmaf(fv, c, iv * gv);
        return ov * tanh2_(c * K2L2E);
    };

    // SY: lanes 0-1 (pmine==0) compute y_prev = W_lin@h2m + b_lin -> s_y.
    // (With h2m == 0 this writes exactly b_lin, the correct t=0 seed.)
    auto SY = [&]() {
        if (u < 2) {
            v2f a0 = ybv0, a1 = ybv1;
            #pragma unroll
            for (int k = 0; k < 5; ++k) {
                a0 = __builtin_elementwise_fma(yl0[k], h2m[k], a0);
                a1 = __builtin_elementwise_fma(yl1[k], h2m[k], a1);
            }
            float2 yv; yv.x = a0.x + a0.y; yv.y = a1.x + a1.y;
            *(float2*)&s_y[slot][2 * u] = yv;
        }
        __builtin_amdgcn_wave_barrier();
    };

    // MAIN(t): gates = wc@h2m + br + wih@(x - y_prev); writes h_t to row t&1;
    // issues readback into h2n (consumed at the TOP of body t+1).
    auto MAIN = [&](int t, float4 xv) {
        float4 yp = *(const float4*)&s_y[slot][0];
        v2f dxa = v2f{xv.x - yp.x, xv.y - yp.y};
        v2f dxc = v2f{xv.z - yp.z, xv.w - yp.w};
        float g[4];
        #pragma unroll
        for (int r = 0; r < 4; ++r) {
            v2f acc = br2[r];
            acc = __builtin_elementwise_fma(wih2[r][0], dxa, acc);
            acc = __builtin_elementwise_fma(wih2[r][1], dxc, acc);
            #pragma unroll
            for (int k = 0; k < 5; ++k)
                acc = __builtin_elementwise_fma(wc2[r][k], h2m[k], acc);
            g[r] = acc.x + acc.y;
        }
        float hn = CELL(g, cm);
        s_h[slot][t & 1][u] = hn;
        __builtin_amdgcn_wave_barrier();
        const v2f* hp = (const v2f*)&s_h[slot][t & 1][0];
        #pragma unroll
        for (int k = 0; k < 5; ++k) h2n[k] = hp[k];
    };

    // ROLLOUT(tt): cells p=1..4 starting from h_tt (= h2m regs), c = cro;
    // then the y phase for step tt (5 outputs), store to outb + tt*20.
    auto ROLLOUT = [&](int tt, float cro) {
        v2f hr2[5];
        #pragma unroll
        for (int k = 0; k < 5; ++k) hr2[k] = h2m[k];
        float cr = cro;
        float g[4];
        #pragma unroll
        for (int p = 1; p < PN; ++p) {
            #pragma unroll
            for (int r = 0; r < 4; ++r) {
                v2f acc = br2[r];
                #pragma unroll
                for (int k = 0; k < 5; ++k)
                    acc = __builtin_elementwise_fma(wc2[r][k], hr2[k], acc);
                g[r] = acc.x + acc.y;
            }
            float hn = CELL(g, cr);
            s_h[slot][1 + p][u] = hn;
            __builtin_amdgcn_wave_barrier();
            if (p < PN - 1) {
                const v2f* hp = (const v2f*)&s_h[slot][1 + p][0];
                #pragma unroll
                for (int k = 0; k < 5; ++k) hr2[k] = hp[k];
            }
        }
        // y phase: lane u outputs y[tt][pmine][opair..opair+1].
        // pmine==0 -> main h_tt at row tt&1 (MAIN(tt+1) wrote the OTHER row);
        // pmine>=1 -> rollout h_p at row pmine+1.
        const int rowy = (pmine == 0) ? (tt & 1) : (pmine + 1);
        const v2f* hq = (const v2f*)&s_h[slot][rowy][0];
        v2f h0 = hq[0], h1 = hq[1], h3 = hq[2], h4 = hq[3], h5 = hq[4];
        v2f a0 = ybv0, a1 = ybv1;
        a0 = __builtin_elementwise_fma(yl0[0], h0, a0);
        a1 = __builtin_elementwise_fma(yl1[0], h0, a1);
        a0 = __builtin_elementwise_fma(yl0[1], h1, a0);
        a1 = __builtin_elementwise_fma(yl1[1], h1, a1);
        a0 = __builtin_elementwise_fma(yl0[2], h3, a0);
        a1 = __builtin_elementwise_fma(yl1[2], h3, a1);
        a0 = __builtin_elementwise_fma(yl0[3], h4, a0);
        a1 = __builtin_elementwise_fma(yl1[3], h4, a1);
        a0 = __builtin_elementwise_fma(yl0[4], h5, a0);
        a1 = __builtin_elementwise_fma(yl1[4], h5, a1);
        float2 yv; yv.x = a0.x + a0.y; yv.y = a1.x + a1.y;
        *(float2*)(outb + tt * PN * OUTN + 2 * u) = yv;
    };

    // ---- prologue: seed s_y (= b_lin, since h2m = 0) and run MAIN(0) ----
    float4 xcur = *(const float4*)xb;
    SY();
    MAIN(0, xcur);                       // h2n = h_0 (pending)
    xcur = *(const float4*)(xb + INPN);

    // ---- pipelined loop: body t = { consume; SY; MAIN(t); ROLLOUT(t-1) } ----
    for (int t = 1; t < TPN; ++t) {
        float4 xnext = *(const float4*)(xb + (t + 1) * INPN);  // t+1 <= 96 < 100
        #pragma unroll
        for (int k = 0; k < 5; ++k) h2m[k] = h2n[k];  // h_{t-1} now available
        float cro = cm;          // c_{t-1}, for the deferred rollout
        SY();                    // s_y = y[t-1][p=0] from h2m (lanes 0-1)
        MAIN(t, xcur);           // uses h2m + s_y; issues h_t readback into h2n
        ROLLOUT(t - 1, cro);     // uses h2m = h_{t-1}; fills the latency window
        xcur = xnext;
    }

    // ---- epilogue: rollout of the last step ----
    #pragma unroll
    for (int k = 0; k < 5; ++k) h2m[k] = h2n[k];      // h_95
    ROLLOUT(TPN - 1, cm);

    // ---- final cell state c (after main_95): [1, B, HID] ----
    out[(long)BN * TPN * PN * OUTN + (long)batch * HIDN + u] = cm;
}

extern "C" void kernel_launch(void* const* d_in, const int* in_sizes, int n_in,
                              void* d_out, int out_size, void* d_ws, size_t ws_size,
                              hipStream_t stream) {
    const float* x     = (const float*)d_in[0];
    const float* W_ih  = (const float*)d_in[1];
    const float* W_hh  = (const float*)d_in[2];
    const float* b_ih  = (const float*)d_in[3];
    const float* b_hh  = (const float*)d_in[4];
    const float* W_lin = (const float*)d_in[5];
    const float* b_lin = (const float*)d_in[6];
    float* out = (float*)d_out;

    const int grid = (BN + GPB - 1) / GPB;  // 683 blocks of 256 threads
    lstm_ar_kernel<<<grid, 256, 0, stream>>>(x, W_ih, W_hh, b_ih, b_hh, W_lin, b_lin, out);
}